// Round 1
// baseline (172.095 us; speedup 1.0000x reference)
//
#include <hip/hip_runtime.h>

typedef _Float16 half_t;
typedef __attribute__((ext_vector_type(8))) _Float16 half8;
typedef __attribute__((ext_vector_type(4))) _Float16 half4;
typedef __attribute__((ext_vector_type(4))) float floatx4;

#define MFMA16(A, B, C) __builtin_amdgcn_mfma_f32_16x16x32_f16((A), (B), (C), 0, 0, 0)

// ---------------------------------------------------------------- k_zero ----
__global__ __launch_bounds__(256) void k_zero(float* __restrict__ p) {
  p[blockIdx.x * 256 + threadIdx.x] = 0.f;  // grid 32 -> 8192 floats
}

// ----------------------------------------------------------------- k_qkv ----
// Per (window, 128-token tile): qkv = Xw(128x64) @ W^T(64x192) + bias.
// Writes q,k as half [win][t][c]; v transposed as vT [win][c][t].
// Accumulates per-window column sums of q,k (post-bias) for the means.
__global__ __launch_bounds__(256) void k_qkv(
    const float* __restrict__ x, const float* __restrict__ W,
    const float* __restrict__ bias, half_t* __restrict__ q,
    half_t* __restrict__ k, half_t* __restrict__ vT,
    float* __restrict__ qsum, float* __restrict__ ksum) {
  __shared__ __align__(16) half_t Xs[128][72];
  __shared__ __align__(16) half_t Ws[192][72];
  __shared__ float qs_l[64], ks_l[64];
  const int w = blockIdx.y;
  const int t0 = blockIdx.x * 128;
  const int ih = w >> 3, iw = w & 7;
  const int xbase = ih * 8192 + iw * 32;  // (ih*32)*256 + iw*32
  const int tid = threadIdx.x;

  // stage X tile transposed: Xs[t_local][c]  (x is [c][h][w])
  for (int i = tid; i < 8192; i += 256) {
    const int c = i >> 7, tt = i & 127;
    const int t = t0 + tt;
    Xs[tt][c] = (half_t)x[c * 65536 + xbase + (t >> 5) * 256 + (t & 31)];
  }
  // stage W: already [o][c] row-major = B-operand layout
  for (int i = tid; i < 12288; i += 256)
    Ws[i >> 6][i & 63] = (half_t)W[i];
  if (tid < 64) { qs_l[tid] = 0.f; ks_l[tid] = 0.f; }
  __syncthreads();

  const int wave = tid >> 6, lane = tid & 63;
  const int lrow = lane & 15, lq = lane >> 4;
  const int rbase = (wave >> 1) * 64;  // 2 row-groups of 64
  const int cbase = (wave & 1) * 96;   // 2 col-groups of 96

  floatx4 acc[4][6];
  const floatx4 z = {0.f, 0.f, 0.f, 0.f};
  #pragma unroll
  for (int mt = 0; mt < 4; mt++)
    #pragma unroll
    for (int nt = 0; nt < 6; nt++) acc[mt][nt] = z;

  #pragma unroll
  for (int kf = 0; kf < 2; kf++) {
    const int koff = kf * 32 + lq * 8;
    half8 a[4], b[6];
    #pragma unroll
    for (int mt = 0; mt < 4; mt++)
      a[mt] = *(const half8*)&Xs[rbase + mt * 16 + lrow][koff];
    #pragma unroll
    for (int nt = 0; nt < 6; nt++)
      b[nt] = *(const half8*)&Ws[cbase + nt * 16 + lrow][koff];
    #pragma unroll
    for (int mt = 0; mt < 4; mt++)
      #pragma unroll
      for (int nt = 0; nt < 6; nt++)
        acc[mt][nt] = MFMA16(a[mt], b[nt], acc[mt][nt]);
  }

  // epilogue: bias add, scatter to q/k/vT, accumulate column sums
  #pragma unroll
  for (int nt = 0; nt < 6; nt++) {
    const int o = cbase + nt * 16 + lrow;
    const float bs = bias[o];
    if (o < 64) {
      float s = 0.f;
      #pragma unroll
      for (int mt = 0; mt < 4; mt++) {
        const int tr = t0 + rbase + mt * 16 + lq * 4;
        #pragma unroll
        for (int r = 0; r < 4; r++) {
          const float v = acc[mt][nt][r] + bs;
          q[w * 65536 + (tr + r) * 64 + o] = (half_t)v;
          s += v;
        }
      }
      atomicAdd(&qs_l[o], s);
    } else if (o < 128) {
      const int oc = o - 64;
      float s = 0.f;
      #pragma unroll
      for (int mt = 0; mt < 4; mt++) {
        const int tr = t0 + rbase + mt * 16 + lq * 4;
        #pragma unroll
        for (int r = 0; r < 4; r++) {
          const float v = acc[mt][nt][r] + bs;
          k[w * 65536 + (tr + r) * 64 + oc] = (half_t)v;
          s += v;
        }
      }
      atomicAdd(&ks_l[oc], s);
    } else {
      const int oc = o - 128;
      #pragma unroll
      for (int mt = 0; mt < 4; mt++) {
        const int tr = t0 + rbase + mt * 16 + lq * 4;  // 4 consecutive t
        half4 pk;
        #pragma unroll
        for (int r = 0; r < 4; r++) pk[r] = (half_t)(acc[mt][nt][r] + bs);
        *(half4*)&vT[w * 65536 + oc * 1024 + tr] = pk;  // 8B store
      }
    }
  }
  __syncthreads();
  if (tid < 64) {
    atomicAdd(&qsum[w * 64 + tid], qs_l[tid]);
    atomicAdd(&ksum[w * 64 + tid], ks_l[tid]);
  }
}

// ------------------------------------------------------------------ k_ar ----
// a_r[i][j] = relu(dot(qsum[i], ksum[j])) / 1024^2
__global__ __launch_bounds__(256) void k_ar(const float* __restrict__ qsum,
                                            const float* __restrict__ ksum,
                                            float* __restrict__ ar) {
  __shared__ float qs[64][65];  // +1 pad: ks[j][c] read has j varying per lane
  __shared__ float ks[64][65];
  const int tid = threadIdx.x;
  for (int i = tid; i < 4096; i += 256) {
    qs[i >> 6][i & 63] = qsum[i];
    ks[i >> 6][i & 63] = ksum[i];
  }
  __syncthreads();
  const float scale = 1.f / (1024.f * 1024.f);
  for (int e = tid; e < 4096; e += 256) {
    const int i = e >> 6, j = e & 63;
    float s = 0.f;
    #pragma unroll
    for (int c = 0; c < 64; c++) s += qs[i][c] * ks[j][c];
    s *= scale;
    ar[e] = s > 0.f ? s : 0.f;
  }
}

// ----------------------------------------------------------------- k_mix ----
// qm[i][pos] = sum_j ar[i][j] * q[j][pos], pos = t*64+c (65536 per window-slab)
// blockIdx.y: 0 -> q->qm, 1 -> k->km. Thread per pos, 64 fp32 accumulators.
__global__ __launch_bounds__(256) void k_mix(const half_t* __restrict__ q,
                                             const half_t* __restrict__ k,
                                             const float* __restrict__ ar,
                                             half_t* __restrict__ qm,
                                             half_t* __restrict__ km) {
  __shared__ __align__(16) float aT[64][68];  // aT[j][i], pad to 68 (16B rows)
  const int tid = threadIdx.x;
  for (int e = tid; e < 4096; e += 256) {
    const int i = e >> 6, j = e & 63;
    aT[j][i] = ar[e];
  }
  __syncthreads();
  const half_t* __restrict__ src = blockIdx.y ? k : q;
  half_t* __restrict__ dst = blockIdx.y ? km : qm;
  const int pos = blockIdx.x * 256 + tid;
  float acc[64];
  #pragma unroll
  for (int i = 0; i < 64; i++) acc[i] = 0.f;
  for (int j = 0; j < 64; j++) {
    const float v = (float)src[j * 65536 + pos];
    #pragma unroll
    for (int i4 = 0; i4 < 16; i4++) {
      const floatx4 a4 = *(const floatx4*)&aT[j][i4 * 4];  // broadcast
      acc[i4 * 4 + 0] += a4[0] * v;
      acc[i4 * 4 + 1] += a4[1] * v;
      acc[i4 * 4 + 2] += a4[2] * v;
      acc[i4 * 4 + 3] += a4[3] * v;
    }
  }
  #pragma unroll
  for (int i = 0; i < 64; i++) dst[i * 65536 + pos] = (half_t)acc[i];
}

// ---------------------------------------------------------------- k_attn ----
// Per (window, 64-token t-tile): O = relu(Qm Km^T) V, streamed over 16
// s-chunks of 64. S goes C-layout -> relu -> fp16 -> LDS -> A-layout.
// Output transposed through LDS for coalesced (c,h,w) fp32 stores.
__global__ __launch_bounds__(256) void k_attn(const half_t* __restrict__ qm,
                                              const half_t* __restrict__ km,
                                              const half_t* __restrict__ vT,
                                              float* __restrict__ out) {
  __shared__ __align__(16) char smem[27648];
  half_t (*Ks)[72] = (half_t (*)[72])(smem);           //  9216 B
  half_t (*Vs)[72] = (half_t (*)[72])(smem + 9216);    //  9216 B
  half_t (*Ss)[72] = (half_t (*)[72])(smem + 18432);   //  9216 B
  float (*Of)[66] = (float (*)[66])(smem);             // 16896 B, overlays Ks/Vs (after barrier)
  const int w = blockIdx.y;
  const int t0 = blockIdx.x * 64;
  const int tid = threadIdx.x;
  const int wave = tid >> 6, lane = tid & 63;
  const int lrow = lane & 15, lq = lane >> 4;
  const int rbase = wave * 16;  // each wave owns a 16-row strip of S/O
  const int wbase = w * 65536;

  // Q A-fragments: resident for the whole block
  half8 aq[2];
  {
    const int t = t0 + rbase + lrow;
    aq[0] = *(const half8*)&qm[wbase + t * 64 + lq * 8];
    aq[1] = *(const half8*)&qm[wbase + t * 64 + 32 + lq * 8];
  }
  const floatx4 z = {0.f, 0.f, 0.f, 0.f};
  floatx4 oacc[4];
  #pragma unroll
  for (int nt = 0; nt < 4; nt++) oacc[nt] = z;

  for (int sc = 0; sc < 16; sc++) {
    const int s0 = sc * 64;
    __syncthreads();  // protect Ks/Vs/Ss reuse from previous iteration
    for (int ch = tid; ch < 512; ch += 256) {
      const int r = ch >> 3, co = (ch & 7) * 8;
      *(half8*)&Ks[r][co] = *(const half8*)&km[wbase + (s0 + r) * 64 + co];
      *(half8*)&Vs[r][co] = *(const half8*)&vT[wbase + r * 1024 + s0 + co];
    }
    __syncthreads();
    // S = Qm(16x64) . Km_chunk^T(64x64)
    floatx4 sacc[4];
    #pragma unroll
    for (int nt = 0; nt < 4; nt++) sacc[nt] = z;
    #pragma unroll
    for (int kf = 0; kf < 2; kf++) {
      const int koff = kf * 32 + lq * 8;
      #pragma unroll
      for (int nt = 0; nt < 4; nt++) {
        const half8 b = *(const half8*)&Ks[nt * 16 + lrow][koff];
        sacc[nt] = MFMA16(aq[kf], b, sacc[nt]);
      }
    }
    // relu -> fp16 -> Ss[t_local][s_local]
    #pragma unroll
    for (int nt = 0; nt < 4; nt++) {
      const int col = nt * 16 + lrow;
      #pragma unroll
      for (int r = 0; r < 4; r++) {
        const float v = sacc[nt][r];
        Ss[rbase + lq * 4 + r][col] = (half_t)(v > 0.f ? v : 0.f);
      }
    }
    __syncthreads();
    // O += S(16x64) . V_chunk(64x64)   (B-rows = vT[c][s])
    #pragma unroll
    for (int kf = 0; kf < 2; kf++) {
      const int koff = kf * 32 + lq * 8;
      const half8 sa = *(const half8*)&Ss[rbase + lrow][koff];
      #pragma unroll
      for (int nt = 0; nt < 4; nt++) {
        const half8 bv = *(const half8*)&Vs[nt * 16 + lrow][koff];
        oacc[nt] = MFMA16(sa, bv, oacc[nt]);
      }
    }
  }
  __syncthreads();
  // transpose O through LDS: Of[c][t_local]
  #pragma unroll
  for (int nt = 0; nt < 4; nt++) {
    const int c = nt * 16 + lrow;
    #pragma unroll
    for (int r = 0; r < 4; r++) Of[c][rbase + lq * 4 + r] = oacc[nt][r];
  }
  __syncthreads();
  const int ih = w >> 3, iw = w & 7;
  const int obase = ih * 8192 + iw * 32;
  for (int i = tid; i < 4096; i += 256) {
    const int c = i >> 6, tl = i & 63;
    const int t = t0 + tl;
    out[c * 65536 + obase + (t >> 5) * 256 + (t & 31)] = Of[c][tl];
  }
}

// ---------------------------------------------------------------- launch ----
extern "C" void kernel_launch(void* const* d_in, const int* in_sizes, int n_in,
                              void* d_out, int out_size, void* d_ws, size_t ws_size,
                              hipStream_t stream) {
  const float* x = (const float*)d_in[0];
  const float* W = (const float*)d_in[1];
  const float* bias = (const float*)d_in[2];
  float* out = (float*)d_out;

  // workspace: 5 x 8MB half buffers + sums/ar (fp32)
  half_t* q = (half_t*)d_ws;
  half_t* k = q + 4194304;
  half_t* vT = k + 4194304;
  half_t* qm = vT + 4194304;
  half_t* km = qm + 4194304;
  float* qsum = (float*)(km + 4194304);
  float* ksum = qsum + 4096;
  float* ar = ksum + 4096;

  k_zero<<<32, 256, 0, stream>>>(qsum);  // zeros qsum+ksum (contiguous 8192)
  k_qkv<<<dim3(8, 64), 256, 0, stream>>>(x, W, bias, q, k, vT, qsum, ksum);
  k_ar<<<1, 256, 0, stream>>>(qsum, ksum, ar);
  k_mix<<<dim3(256, 2), 256, 0, stream>>>(q, k, ar, qm, km);
  k_attn<<<dim3(16, 64), 256, 0, stream>>>(qm, km, vT, out);
}

// Round 3
// 152.885 us; speedup vs baseline: 1.1257x; 1.1257x over previous
//
#include <hip/hip_runtime.h>

typedef _Float16 half_t;
typedef __attribute__((ext_vector_type(8))) _Float16 half8;
typedef __attribute__((ext_vector_type(4))) _Float16 half4;
typedef __attribute__((ext_vector_type(2))) _Float16 half2_t;
typedef __attribute__((ext_vector_type(4))) float floatx4;
typedef __attribute__((ext_vector_type(16))) float floatx16;

#define MFMA16(A, B, C) __builtin_amdgcn_mfma_f32_16x16x32_f16((A), (B), (C), 0, 0, 0)
#define MFMA32(A, B, C) __builtin_amdgcn_mfma_f32_32x32x16_f16((A), (B), (C), 0, 0, 0)

// ----------------------------------------------------------------- k_qkv ----
// Per (t-tile tx, window w): qkv = Xw(128x64) @ W^T(64x192) + bias.
// Writes q,k as half [win][t][c]; v transposed as vT [win][c][t].
// Per-block column sums of q,k -> partial arrays qp/kp[(w*8+tx)*64+c].
__global__ __launch_bounds__(256) void k_qkv(
    const float* __restrict__ x, const float* __restrict__ W,
    const float* __restrict__ bias, half_t* __restrict__ q,
    half_t* __restrict__ k, half_t* __restrict__ vT,
    float* __restrict__ qp, float* __restrict__ kp) {
  __shared__ __align__(16) half_t Xs[128][72];
  __shared__ __align__(16) half_t Ws[192][72];
  __shared__ float qs_l[64], ks_l[64];
  const int w = blockIdx.y;
  const int tx = blockIdx.x;
  const int t0 = tx * 128;
  const int ih = w >> 3, iw = w & 7;
  const int xbase = ih * 8192 + iw * 32;
  const int tid = threadIdx.x;

  for (int i = tid; i < 8192; i += 256) {
    const int c = i >> 7, tt = i & 127;
    const int t = t0 + tt;
    Xs[tt][c] = (half_t)x[c * 65536 + xbase + (t >> 5) * 256 + (t & 31)];
  }
  for (int i = tid; i < 12288; i += 256)
    Ws[i >> 6][i & 63] = (half_t)W[i];
  if (tid < 64) { qs_l[tid] = 0.f; ks_l[tid] = 0.f; }
  __syncthreads();

  const int wave = tid >> 6, lane = tid & 63;
  const int lrow = lane & 15, lq = lane >> 4;
  const int rbase = (wave >> 1) * 64;
  const int cbase = (wave & 1) * 96;

  floatx4 acc[4][6];
  const floatx4 z = {0.f, 0.f, 0.f, 0.f};
  #pragma unroll
  for (int mt = 0; mt < 4; mt++)
    #pragma unroll
    for (int nt = 0; nt < 6; nt++) acc[mt][nt] = z;

  #pragma unroll
  for (int kf = 0; kf < 2; kf++) {
    const int koff = kf * 32 + lq * 8;
    half8 a[4], b[6];
    #pragma unroll
    for (int mt = 0; mt < 4; mt++)
      a[mt] = *(const half8*)&Xs[rbase + mt * 16 + lrow][koff];
    #pragma unroll
    for (int nt = 0; nt < 6; nt++)
      b[nt] = *(const half8*)&Ws[cbase + nt * 16 + lrow][koff];
    #pragma unroll
    for (int mt = 0; mt < 4; mt++)
      #pragma unroll
      for (int nt = 0; nt < 6; nt++)
        acc[mt][nt] = MFMA16(a[mt], b[nt], acc[mt][nt]);
  }

  #pragma unroll
  for (int nt = 0; nt < 6; nt++) {
    const int o = cbase + nt * 16 + lrow;
    const float bs = bias[o];
    if (o < 64) {
      float s = 0.f;
      #pragma unroll
      for (int mt = 0; mt < 4; mt++) {
        const int tr = t0 + rbase + mt * 16 + lq * 4;
        #pragma unroll
        for (int r = 0; r < 4; r++) {
          const float v = acc[mt][nt][r] + bs;
          q[w * 65536 + (tr + r) * 64 + o] = (half_t)v;
          s += v;
        }
      }
      atomicAdd(&qs_l[o], s);
    } else if (o < 128) {
      const int oc = o - 64;
      float s = 0.f;
      #pragma unroll
      for (int mt = 0; mt < 4; mt++) {
        const int tr = t0 + rbase + mt * 16 + lq * 4;
        #pragma unroll
        for (int r = 0; r < 4; r++) {
          const float v = acc[mt][nt][r] + bs;
          k[w * 65536 + (tr + r) * 64 + oc] = (half_t)v;
          s += v;
        }
      }
      atomicAdd(&ks_l[oc], s);
    } else {
      const int oc = o - 128;
      #pragma unroll
      for (int mt = 0; mt < 4; mt++) {
        const int tr = t0 + rbase + mt * 16 + lq * 4;
        half4 pk;
        #pragma unroll
        for (int r = 0; r < 4; r++) pk[r] = (half_t)(acc[mt][nt][r] + bs);
        *(half4*)&vT[w * 65536 + oc * 1024 + tr] = pk;
      }
    }
  }
  __syncthreads();
  if (tid < 64) {
    qp[(w * 8 + tx) * 64 + tid] = qs_l[tid];
    kp[(w * 8 + tx) * 64 + tid] = ks_l[tid];
  }
}

// ------------------------------------------------------------------ k_ar ----
// Reduce per-tile partial sums, then a_r[i][j] = relu(qsum_i . ksum_j)/1024^2
__global__ __launch_bounds__(256) void k_ar(const float* __restrict__ qp,
                                            const float* __restrict__ kp,
                                            float* __restrict__ ar) {
  __shared__ float qs[64][65];
  __shared__ float ks[64][65];
  const int tid = threadIdx.x;
  for (int e = tid; e < 4096; e += 256) {
    const int i = e >> 6, c = e & 63;
    float sq = 0.f, sk = 0.f;
    #pragma unroll
    for (int t = 0; t < 8; t++) {
      sq += qp[i * 512 + t * 64 + c];
      sk += kp[i * 512 + t * 64 + c];
    }
    qs[i][c] = sq;
    ks[i][c] = sk;
  }
  __syncthreads();
  const float scale = 1.f / (1024.f * 1024.f);
  const int e = blockIdx.x * 256 + tid;  // grid 16 -> 4096 outputs
  const int i = e >> 6, j = e & 63;
  float s = 0.f;
  #pragma unroll
  for (int c = 0; c < 64; c++) s += qs[i][c] * ks[j][c];
  s *= scale;
  ar[e] = s > 0.f ? s : 0.f;
}

// ----------------------------------------------------------------- k_mix ----
// qm[i][pos] = sum_j ar[i][j] * q[j][pos]. 2 pos/thread, acc in 128 VGPRs;
// ar rows broadcast from LDS float4 (16 reads amortized over 256 FMAs).
__global__ __launch_bounds__(256) void k_mix(const half_t* __restrict__ q,
                                             const half_t* __restrict__ k,
                                             const float* __restrict__ ar,
                                             half_t* __restrict__ qm,
                                             half_t* __restrict__ km) {
  __shared__ __align__(16) float aT[64][68];  // aT[j][i]
  const int tid = threadIdx.x;
  for (int e = tid; e < 4096; e += 256) {
    const int j = e >> 6, i = e & 63;       // lane-consecutive i -> conflict-free write
    aT[j][i] = ar[i * 64 + j];              // scattered read, L1-cached (16 KB)
  }
  __syncthreads();
  const half_t* __restrict__ src = blockIdx.y ? k : q;
  half_t* __restrict__ dst = blockIdx.y ? km : qm;
  const int p0 = blockIdx.x * 512 + tid * 2;
  float acc0[64], acc1[64];
  #pragma unroll
  for (int i = 0; i < 64; i++) { acc0[i] = 0.f; acc1[i] = 0.f; }

  half2_t va = *(const half2_t*)&src[p0];
  half2_t vb = *(const half2_t*)&src[65536 + p0];
  for (int j = 0; j < 64; j++) {
    const float v0 = (float)va[0], v1 = (float)va[1];
    va = vb;
    if (j < 62) vb = *(const half2_t*)&src[(j + 2) * 65536 + p0];
    #pragma unroll
    for (int i4 = 0; i4 < 16; i4++) {
      const floatx4 a4 = *(const floatx4*)&aT[j][i4 * 4];  // wave-uniform broadcast
      #pragma unroll
      for (int p = 0; p < 4; p++) {
        acc0[i4 * 4 + p] += a4[p] * v0;
        acc1[i4 * 4 + p] += a4[p] * v1;
      }
    }
  }
  #pragma unroll
  for (int i = 0; i < 64; i++) {
    half2_t o;
    o[0] = (half_t)acc0[i];
    o[1] = (half_t)acc1[i];
    *(half2_t*)&dst[i * 65536 + p0] = o;
  }
}

// ---------------------------------------------------------------- k_attn ----
// Per (t-tile of 128, window): O = relu(Qm Km^T) V over 8 s-chunks of 128.
// 32x32x16 MFMA. Q register-resident as B-frags (S^T = K.Q^T), St packed
// half4 writes, O transposed via LDS for coalesced fp32 stores.
__global__ __launch_bounds__(256, 2) void k_attn(const half_t* __restrict__ qm,
                                                 const half_t* __restrict__ km,
                                                 const half_t* __restrict__ vT,
                                                 float* __restrict__ out) {
  __shared__ __align__(16) char smem[70656];
  half_t (*Ks)[72]  = (half_t (*)[72])(smem);            // 18432 B  [s][c]
  half_t (*Vs)[136] = (half_t (*)[136])(smem + 18432);   // 17408 B  [c][s]
  half_t (*St)[136] = (half_t (*)[136])(smem + 35840);   // 34816 B  [t][s]
  half_t (*Qs)[72]  = (half_t (*)[72])(smem + 35840);    // overlays St (pre-loop)
  float (*Of)[132]  = (float (*)[132])(smem);            // 33792 B, overlays Ks+Vs

  const int w = blockIdx.y;
  const int t0 = blockIdx.x * 128;
  const int tid = threadIdx.x;
  const int wave = tid >> 6, lane = tid & 63;
  const int ln31 = lane & 31;
  const int hk8 = (lane >> 5) * 8, hk4 = (lane >> 5) * 4;
  const int w32 = wave * 32;
  const int wbase = w * 65536;

  // stage Q tile [128][64] once (full coverage: 1024 x half8 = 8192 halves)
  for (int idx = tid; idx < 1024; idx += 256) {
    const int r = idx >> 3, co = (idx & 7) * 8;
    *(half8*)&Qs[r][co] = *(const half8*)&qm[wbase + (t0 + r) * 64 + co];
  }
  __syncthreads();
  // Q as B-fragments, resident: bQ[tt][kk], tt = t-tile of 32, kk = k-step of 16
  half8 bQ[4][4];
  #pragma unroll
  for (int tt = 0; tt < 4; tt++)
    #pragma unroll
    for (int kk = 0; kk < 4; kk++)
      bQ[tt][kk] = *(const half8*)&Qs[tt * 32 + ln31][kk * 16 + hk8];

  floatx16 oacc[2];
  #pragma unroll
  for (int ct = 0; ct < 2; ct++)
    #pragma unroll
    for (int r = 0; r < 16; r++) oacc[ct][r] = 0.f;

  for (int sc = 0; sc < 8; sc++) {
    const int s0 = sc * 128;
    __syncthreads();  // previous chunk's reads done (and Q-frag reads, first iter)
    for (int idx = tid; idx < 1024; idx += 256) {
      const int r = idx >> 3, co = (idx & 7) * 8;
      *(half8*)&Ks[r][co] = *(const half8*)&km[wbase + (s0 + r) * 64 + co];
    }
    for (int idx = tid; idx < 1024; idx += 256) {
      const int c = idx >> 4, so = (idx & 15) * 8;
      *(half8*)&Vs[c][so] = *(const half8*)&vT[wbase + c * 1024 + s0 + so];
    }
    __syncthreads();

    // S^T[s][t] = sum_c K[s][c] Q[t][c]; wave owns s-rows [32*wave, +32)
    floatx16 sacc[4];
    #pragma unroll
    for (int tt = 0; tt < 4; tt++)
      #pragma unroll
      for (int r = 0; r < 16; r++) sacc[tt][r] = 0.f;
    half8 aK[4];
    #pragma unroll
    for (int kk = 0; kk < 4; kk++)
      aK[kk] = *(const half8*)&Ks[w32 + ln31][kk * 16 + hk8];
    #pragma unroll
    for (int kk = 0; kk < 4; kk++)
      #pragma unroll
      for (int tt = 0; tt < 4; tt++)
        sacc[tt] = MFMA32(aK[kk], bQ[tt][kk], sacc[tt]);

    // relu -> packed half4 -> St[t][s]
    #pragma unroll
    for (int tt = 0; tt < 4; tt++) {
      const int t = tt * 32 + ln31;
      #pragma unroll
      for (int g = 0; g < 4; g++) {
        const int s = w32 + g * 8 + hk4;
        half4 pk;
        #pragma unroll
        for (int p = 0; p < 4; p++) {
          const float v = sacc[tt][g * 4 + p];
          pk[p] = (half_t)(v > 0.f ? v : 0.f);
        }
        *(half4*)&St[t][s] = pk;
      }
    }
    __syncthreads();

    // O[t][c] += sum_s St[t][s] V[s][c]; wave owns t-rows [32*wave, +32)
    #pragma unroll
    for (int kk = 0; kk < 8; kk++) {
      const half8 aS = *(const half8*)&St[w32 + ln31][kk * 16 + hk8];
      #pragma unroll
      for (int ct = 0; ct < 2; ct++) {
        const half8 bV = *(const half8*)&Vs[ct * 32 + ln31][kk * 16 + hk8];
        oacc[ct] = MFMA32(aS, bV, oacc[ct]);
      }
    }
  }
  __syncthreads();
  // transpose O via LDS: Of[c][t_local], packed float4 (rows t consecutive)
  #pragma unroll
  for (int ct = 0; ct < 2; ct++) {
    const int c = ct * 32 + ln31;
    #pragma unroll
    for (int g = 0; g < 4; g++) {
      const int tl = w32 + g * 8 + hk4;
      floatx4 f;
      #pragma unroll
      for (int p = 0; p < 4; p++) f[p] = oacc[ct][g * 4 + p];
      *(floatx4*)&Of[c][tl] = f;
    }
  }
  __syncthreads();
  const int ih = w >> 3, iw = w & 7;
  const int obase = ih * 8192 + iw * 32;
  for (int i = tid; i < 8192; i += 256) {
    const int c = i >> 7, tl = i & 127;
    const int t = t0 + tl;
    out[c * 65536 + obase + (t >> 5) * 256 + (t & 31)] = Of[c][tl];
  }
}

// ---------------------------------------------------------------- launch ----
extern "C" void kernel_launch(void* const* d_in, const int* in_sizes, int n_in,
                              void* d_out, int out_size, void* d_ws, size_t ws_size,
                              hipStream_t stream) {
  const float* x = (const float*)d_in[0];
  const float* W = (const float*)d_in[1];
  const float* bias = (const float*)d_in[2];
  float* out = (float*)d_out;

  half_t* q = (half_t*)d_ws;
  half_t* k = q + 4194304;
  half_t* vT = k + 4194304;
  half_t* qm = vT + 4194304;
  half_t* km = qm + 4194304;
  float* qp = (float*)(km + 4194304);  // 512*64
  float* kp = qp + 32768;
  float* ar = kp + 32768;              // 4096

  k_qkv<<<dim3(8, 64), 256, 0, stream>>>(x, W, bias, q, k, vT, qp, kp);
  k_ar<<<16, 256, 0, stream>>>(qp, kp, ar);
  k_mix<<<dim3(128, 2), 256, 0, stream>>>(q, k, ar, qm, km);
  k_attn<<<dim3(8, 64), 256, 0, stream>>>(qm, km, vT, out);
}

// Round 4
// 132.296 us; speedup vs baseline: 1.3008x; 1.1556x over previous
//
#include <hip/hip_runtime.h>

typedef _Float16 half_t;
typedef __attribute__((ext_vector_type(8))) _Float16 half8;
typedef __attribute__((ext_vector_type(4))) _Float16 half4;
typedef __attribute__((ext_vector_type(4))) float floatx4;
typedef __attribute__((ext_vector_type(16))) float floatx16;

#define MFMA16(A, B, C) __builtin_amdgcn_mfma_f32_16x16x32_f16((A), (B), (C), 0, 0, 0)
#define MFMA32(A, B, C) __builtin_amdgcn_mfma_f32_32x32x16_f16((A), (B), (C), 0, 0, 0)

// ----------------------------------------------------------------- k_qkv ----
// Per (t-tile tx, window w): qkv = Xw(128x64) @ W^T(64x192) + bias.
// Writes q,k as half [win][t][c]; v transposed as vT [win][c][t].
// Per-block column sums of q,k -> partial arrays qp/kp[(w*8+tx)*64+c].
__global__ __launch_bounds__(256) void k_qkv(
    const float* __restrict__ x, const float* __restrict__ W,
    const float* __restrict__ bias, half_t* __restrict__ q,
    half_t* __restrict__ k, half_t* __restrict__ vT,
    float* __restrict__ qp, float* __restrict__ kp) {
  __shared__ __align__(16) half_t Xs[128][72];
  __shared__ __align__(16) half_t Ws[192][72];
  __shared__ float qs_l[64], ks_l[64];
  const int w = blockIdx.y;
  const int tx = blockIdx.x;
  const int t0 = tx * 128;
  const int ih = w >> 3, iw = w & 7;
  const int xbase = ih * 8192 + iw * 32;
  const int tid = threadIdx.x;

  for (int i = tid; i < 8192; i += 256) {
    const int c = i >> 7, tt = i & 127;
    const int t = t0 + tt;
    Xs[tt][c] = (half_t)x[c * 65536 + xbase + (t >> 5) * 256 + (t & 31)];
  }
  // W staged as float4 -> half4 (conflict-free b64 LDS writes)
  for (int i = tid; i < 3072; i += 256) {
    const int o = i >> 4, c4 = (i & 15) * 4;
    const floatx4 v = *(const floatx4*)&W[o * 64 + c4];
    half4 hv;
    #pragma unroll
    for (int p = 0; p < 4; p++) hv[p] = (half_t)v[p];
    *(half4*)&Ws[o][c4] = hv;
  }
  if (tid < 64) { qs_l[tid] = 0.f; ks_l[tid] = 0.f; }
  __syncthreads();

  const int wave = tid >> 6, lane = tid & 63;
  const int lrow = lane & 15, lq = lane >> 4;
  const int rbase = (wave >> 1) * 64;
  const int cbase = (wave & 1) * 96;

  floatx4 acc[4][6];
  const floatx4 z = {0.f, 0.f, 0.f, 0.f};
  #pragma unroll
  for (int mt = 0; mt < 4; mt++)
    #pragma unroll
    for (int nt = 0; nt < 6; nt++) acc[mt][nt] = z;

  #pragma unroll
  for (int kf = 0; kf < 2; kf++) {
    const int koff = kf * 32 + lq * 8;
    half8 a[4], b[6];
    #pragma unroll
    for (int mt = 0; mt < 4; mt++)
      a[mt] = *(const half8*)&Xs[rbase + mt * 16 + lrow][koff];
    #pragma unroll
    for (int nt = 0; nt < 6; nt++)
      b[nt] = *(const half8*)&Ws[cbase + nt * 16 + lrow][koff];
    #pragma unroll
    for (int mt = 0; mt < 4; mt++)
      #pragma unroll
      for (int nt = 0; nt < 6; nt++)
        acc[mt][nt] = MFMA16(a[mt], b[nt], acc[mt][nt]);
  }

  #pragma unroll
  for (int nt = 0; nt < 6; nt++) {
    const int o = cbase + nt * 16 + lrow;
    const float bs = bias[o];
    if (o < 64) {
      float s = 0.f;
      #pragma unroll
      for (int mt = 0; mt < 4; mt++) {
        const int tr = t0 + rbase + mt * 16 + lq * 4;
        #pragma unroll
        for (int r = 0; r < 4; r++) {
          const float v = acc[mt][nt][r] + bs;
          q[w * 65536 + (tr + r) * 64 + o] = (half_t)v;
          s += v;
        }
      }
      atomicAdd(&qs_l[o], s);
    } else if (o < 128) {
      const int oc = o - 64;
      float s = 0.f;
      #pragma unroll
      for (int mt = 0; mt < 4; mt++) {
        const int tr = t0 + rbase + mt * 16 + lq * 4;
        #pragma unroll
        for (int r = 0; r < 4; r++) {
          const float v = acc[mt][nt][r] + bs;
          k[w * 65536 + (tr + r) * 64 + oc] = (half_t)v;
          s += v;
        }
      }
      atomicAdd(&ks_l[oc], s);
    } else {
      const int oc = o - 128;
      #pragma unroll
      for (int mt = 0; mt < 4; mt++) {
        const int tr = t0 + rbase + mt * 16 + lq * 4;
        half4 pk;
        #pragma unroll
        for (int r = 0; r < 4; r++) pk[r] = (half_t)(acc[mt][nt][r] + bs);
        *(half4*)&vT[w * 65536 + oc * 1024 + tr] = pk;
      }
    }
  }
  __syncthreads();
  if (tid < 64) {
    qp[(w * 8 + tx) * 64 + tid] = qs_l[tid];
    kp[(w * 8 + tx) * 64 + tid] = ks_l[tid];
  }
}

// ------------------------------------------------------------------ k_ar ----
// Reduce per-tile partials; arH[i][j] = (half)relu(qsum_i . ksum_j)/1024^2
__global__ __launch_bounds__(256) void k_ar(const float* __restrict__ qp,
                                            const float* __restrict__ kp,
                                            half_t* __restrict__ arH) {
  __shared__ float qs[64][65];
  __shared__ float ks[64][65];
  const int tid = threadIdx.x;
  for (int e = tid; e < 4096; e += 256) {
    const int i = e >> 6, c = e & 63;
    float sq = 0.f, sk = 0.f;
    #pragma unroll
    for (int t = 0; t < 8; t++) {
      sq += qp[i * 512 + t * 64 + c];
      sk += kp[i * 512 + t * 64 + c];
    }
    qs[i][c] = sq;
    ks[i][c] = sk;
  }
  __syncthreads();
  const float scale = 1.f / (1024.f * 1024.f);
  const int e = blockIdx.x * 256 + tid;  // grid 16 -> 4096 outputs
  const int i = e >> 6, j = e & 63;
  float s = 0.f;
  #pragma unroll
  for (int c = 0; c < 64; c++) s += qs[i][c] * ks[j][c];
  s *= scale;
  arH[e] = (half_t)(s > 0.f ? s : 0.f);
}

// ----------------------------------------------------------------- k_mix ----
// MFMA GEMM: D[i][pos] = sum_j arH[i][j] * src[j][pos].  M=64(i), K=64(j),
// N=65536(pos). A-frags = arH rows (b128, L1-hot). B-frags assembled from
// coalesced scalar u16 global loads (lane n=pos). C stored as coalesced u16.
// No LDS, no barriers. grid (256, 2): wave handles 2 pos-tiles of 32.
__global__ __launch_bounds__(256) void k_mix(const half_t* __restrict__ q,
                                             const half_t* __restrict__ k,
                                             const half_t* __restrict__ arH,
                                             half_t* __restrict__ qm,
                                             half_t* __restrict__ km) {
  const half_t* __restrict__ src = blockIdx.y ? k : q;
  half_t* __restrict__ dst = blockIdx.y ? km : qm;
  const int tid = threadIdx.x;
  const int wave = tid >> 6, lane = tid & 63;
  const int ln31 = lane & 31;
  const int hk8 = (lane >> 5) * 8;

  // A-frags: A[m=i][k=j], i = mt*32 + ln31, j = kk*16 + hk8 + jj
  half8 aA[2][4];
  #pragma unroll
  for (int mt = 0; mt < 2; mt++)
    #pragma unroll
    for (int kk = 0; kk < 4; kk++)
      aA[mt][kk] = *(const half8*)&arH[(mt * 32 + ln31) * 64 + kk * 16 + hk8];

  #pragma unroll
  for (int t32 = 0; t32 < 2; t32++) {
    const int pos = blockIdx.x * 256 + wave * 64 + t32 * 32 + ln31;
    // B-frags: B[k=j][n=pos]
    half8 bB[4];
    #pragma unroll
    for (int kk = 0; kk < 4; kk++)
      #pragma unroll
      for (int jj = 0; jj < 8; jj++)
        bB[kk][jj] = src[(kk * 16 + hk8 + jj) * 65536 + pos];

    floatx16 c0, c1;
    #pragma unroll
    for (int r = 0; r < 16; r++) { c0[r] = 0.f; c1[r] = 0.f; }
    #pragma unroll
    for (int kk = 0; kk < 4; kk++) {
      c0 = MFMA32(aA[0][kk], bB[kk], c0);
      c1 = MFMA32(aA[1][kk], bB[kk], c1);
    }
    // store: i = mt*32 + (r&3) + 4*(lane>>5) + 8*(r>>2), coalesced u16
    const int h4 = (lane >> 5) * 4;
    #pragma unroll
    for (int r = 0; r < 16; r++) {
      const int row = (r & 3) + h4 + 8 * (r >> 2);
      dst[row * 65536 + pos] = (half_t)c0[r];
      dst[(32 + row) * 65536 + pos] = (half_t)c1[r];
    }
  }
}

// ---------------------------------------------------------------- k_attn ----
// Per (t-tile of 128, window): O = relu(Qm Km^T) V over 8 s-chunks of 128.
// 32x32x16 MFMA. Q register-resident as B-frags loaded DIRECT from global
// (L1-amortized over 8 chunks); St packed half4; O via LDS transpose,
// float4 stores.
__global__ __launch_bounds__(256, 2) void k_attn(const half_t* __restrict__ qm,
                                                 const half_t* __restrict__ km,
                                                 const half_t* __restrict__ vT,
                                                 float* __restrict__ out) {
  __shared__ __align__(16) char smem[70656];
  half_t (*Ks)[72]  = (half_t (*)[72])(smem);            // 18432 B  [s][c]
  half_t (*Vs)[136] = (half_t (*)[136])(smem + 18432);   // 17408 B  [c][s]
  half_t (*St)[136] = (half_t (*)[136])(smem + 35840);   // 34816 B  [t][s]
  float (*Of)[132]  = (float (*)[132])(smem);            // 67584 B, post-loop

  const int w = blockIdx.y;
  const int t0 = blockIdx.x * 128;
  const int tid = threadIdx.x;
  const int wave = tid >> 6, lane = tid & 63;
  const int ln31 = lane & 31;
  const int hk8 = (lane >> 5) * 8, hk4 = (lane >> 5) * 4;
  const int w32 = wave * 32;
  const int wbase = w * 65536;

  // Q as B-fragments direct from global: B[k=c][n=t]
  half8 bQ[4][4];
  #pragma unroll
  for (int tt = 0; tt < 4; tt++)
    #pragma unroll
    for (int kk = 0; kk < 4; kk++)
      bQ[tt][kk] = *(const half8*)&qm[wbase + (t0 + tt * 32 + ln31) * 64 + kk * 16 + hk8];

  floatx16 oacc[2];
  #pragma unroll
  for (int ct = 0; ct < 2; ct++)
    #pragma unroll
    for (int r = 0; r < 16; r++) oacc[ct][r] = 0.f;

  for (int sc = 0; sc < 8; sc++) {
    const int s0 = sc * 128;
    __syncthreads();  // previous chunk's reads done
    for (int idx = tid; idx < 1024; idx += 256) {
      const int r = idx >> 3, co = (idx & 7) * 8;
      *(half8*)&Ks[r][co] = *(const half8*)&km[wbase + (s0 + r) * 64 + co];
    }
    for (int idx = tid; idx < 1024; idx += 256) {
      const int c = idx >> 4, so = (idx & 15) * 8;
      *(half8*)&Vs[c][so] = *(const half8*)&vT[wbase + c * 1024 + s0 + so];
    }
    __syncthreads();

    // S^T[s][t] = sum_c K[s][c] Q[t][c]; wave owns s-rows [32*wave, +32)
    floatx16 sacc[4];
    #pragma unroll
    for (int tt = 0; tt < 4; tt++)
      #pragma unroll
      for (int r = 0; r < 16; r++) sacc[tt][r] = 0.f;
    half8 aK[4];
    #pragma unroll
    for (int kk = 0; kk < 4; kk++)
      aK[kk] = *(const half8*)&Ks[w32 + ln31][kk * 16 + hk8];
    #pragma unroll
    for (int kk = 0; kk < 4; kk++)
      #pragma unroll
      for (int tt = 0; tt < 4; tt++)
        sacc[tt] = MFMA32(aK[kk], bQ[tt][kk], sacc[tt]);

    // relu -> packed half4 -> St[t][s]
    #pragma unroll
    for (int tt = 0; tt < 4; tt++) {
      const int t = tt * 32 + ln31;
      #pragma unroll
      for (int g = 0; g < 4; g++) {
        const int s = w32 + g * 8 + hk4;
        half4 pk;
        #pragma unroll
        for (int p = 0; p < 4; p++) {
          const float v = sacc[tt][g * 4 + p];
          pk[p] = (half_t)(v > 0.f ? v : 0.f);
        }
        *(half4*)&St[t][s] = pk;
      }
    }
    __syncthreads();

    // O[t][c] += sum_s St[t][s] V[s][c]; wave owns t-rows [32*wave, +32)
    #pragma unroll
    for (int kk = 0; kk < 8; kk++) {
      const half8 aS = *(const half8*)&St[w32 + ln31][kk * 16 + hk8];
      #pragma unroll
      for (int ct = 0; ct < 2; ct++) {
        const half8 bV = *(const half8*)&Vs[ct * 32 + ln31][kk * 16 + hk8];
        oacc[ct] = MFMA32(aS, bV, oacc[ct]);
      }
    }
  }
  __syncthreads();
  // transpose O via LDS: Of[c][t_local], packed float4
  #pragma unroll
  for (int ct = 0; ct < 2; ct++) {
    const int c = ct * 32 + ln31;
    #pragma unroll
    for (int g = 0; g < 4; g++) {
      const int tl = w32 + g * 8 + hk4;
      floatx4 f;
      #pragma unroll
      for (int p = 0; p < 4; p++) f[p] = oacc[ct][g * 4 + p];
      *(floatx4*)&Of[c][tl] = f;
    }
  }
  __syncthreads();
  const int ih = w >> 3, iw = w & 7;
  const int obase = ih * 8192 + iw * 32;
  for (int i = tid; i < 2048; i += 256) {
    const int c = i >> 5, tq = (i & 31) * 4;
    const int t = t0 + tq;
    *(floatx4*)&out[c * 65536 + obase + (t >> 5) * 256 + (t & 31)] =
        *(const floatx4*)&Of[c][tq];
  }
}

// ---------------------------------------------------------------- launch ----
extern "C" void kernel_launch(void* const* d_in, const int* in_sizes, int n_in,
                              void* d_out, int out_size, void* d_ws, size_t ws_size,
                              hipStream_t stream) {
  const float* x = (const float*)d_in[0];
  const float* W = (const float*)d_in[1];
  const float* bias = (const float*)d_in[2];
  float* out = (float*)d_out;

  half_t* q = (half_t*)d_ws;
  half_t* k = q + 4194304;
  half_t* vT = k + 4194304;
  half_t* qm = vT + 4194304;
  half_t* km = qm + 4194304;
  float* qp = (float*)(km + 4194304);  // 512*64
  float* kp = qp + 32768;
  half_t* arH = (half_t*)(kp + 32768); // 4096, 16B-aligned

  k_qkv<<<dim3(8, 64), 256, 0, stream>>>(x, W, bias, q, k, vT, qp, kp);
  k_ar<<<16, 256, 0, stream>>>(qp, kp, arH);
  k_mix<<<dim3(256, 2), 256, 0, stream>>>(q, k, arH, qm, km);
  k_attn<<<dim3(8, 64), 256, 0, stream>>>(qm, km, vT, out);
}

// Round 5
// 129.416 us; speedup vs baseline: 1.3298x; 1.0223x over previous
//
#include <hip/hip_runtime.h>

typedef _Float16 half_t;
typedef __attribute__((ext_vector_type(8))) _Float16 half8;
typedef __attribute__((ext_vector_type(4))) _Float16 half4;
typedef __attribute__((ext_vector_type(4))) float floatx4;
typedef __attribute__((ext_vector_type(16))) float floatx16;

#define MFMA16(A, B, C) __builtin_amdgcn_mfma_f32_16x16x32_f16((A), (B), (C), 0, 0, 0)
#define MFMA32(A, B, C) __builtin_amdgcn_mfma_f32_32x32x16_f16((A), (B), (C), 0, 0, 0)

// ----------------------------------------------------------------- k_qkv ----
// Per (t-tile tx, window w): qkv = Xw(128x64) @ W^T(64x192) + bias.
// Writes q,k as half [win][t][c]; v transposed as vT [win][c][t].
// Per-block column sums of q,k -> partial arrays qp/kp[(w*8+tx)*64+c].
__global__ __launch_bounds__(256) void k_qkv(
    const float* __restrict__ x, const float* __restrict__ W,
    const float* __restrict__ bias, half_t* __restrict__ q,
    half_t* __restrict__ k, half_t* __restrict__ vT,
    float* __restrict__ qp, float* __restrict__ kp) {
  __shared__ __align__(16) half_t Xs[128][72];
  __shared__ __align__(16) half_t Ws[192][72];
  __shared__ float qs_l[64], ks_l[64];
  const int w = blockIdx.y;
  const int tx = blockIdx.x;
  const int t0 = tx * 128;
  const int ih = w >> 3, iw = w & 7;
  const int xbase = ih * 8192 + iw * 32;
  const int tid = threadIdx.x;

  for (int i = tid; i < 8192; i += 256) {
    const int c = i >> 7, tt = i & 127;
    const int t = t0 + tt;
    Xs[tt][c] = (half_t)x[c * 65536 + xbase + (t >> 5) * 256 + (t & 31)];
  }
  // W staged as float4 -> half4 (conflict-free b64 LDS writes)
  for (int i = tid; i < 3072; i += 256) {
    const int o = i >> 4, c4 = (i & 15) * 4;
    const floatx4 v = *(const floatx4*)&W[o * 64 + c4];
    half4 hv;
    #pragma unroll
    for (int p = 0; p < 4; p++) hv[p] = (half_t)v[p];
    *(half4*)&Ws[o][c4] = hv;
  }
  if (tid < 64) { qs_l[tid] = 0.f; ks_l[tid] = 0.f; }
  __syncthreads();

  const int wave = tid >> 6, lane = tid & 63;
  const int lrow = lane & 15, lq = lane >> 4;
  const int rbase = (wave >> 1) * 64;
  const int cbase = (wave & 1) * 96;

  floatx4 acc[4][6];
  const floatx4 z = {0.f, 0.f, 0.f, 0.f};
  #pragma unroll
  for (int mt = 0; mt < 4; mt++)
    #pragma unroll
    for (int nt = 0; nt < 6; nt++) acc[mt][nt] = z;

  #pragma unroll
  for (int kf = 0; kf < 2; kf++) {
    const int koff = kf * 32 + lq * 8;
    half8 a[4], b[6];
    #pragma unroll
    for (int mt = 0; mt < 4; mt++)
      a[mt] = *(const half8*)&Xs[rbase + mt * 16 + lrow][koff];
    #pragma unroll
    for (int nt = 0; nt < 6; nt++)
      b[nt] = *(const half8*)&Ws[cbase + nt * 16 + lrow][koff];
    #pragma unroll
    for (int mt = 0; mt < 4; mt++)
      #pragma unroll
      for (int nt = 0; nt < 6; nt++)
        acc[mt][nt] = MFMA16(a[mt], b[nt], acc[mt][nt]);
  }

  #pragma unroll
  for (int nt = 0; nt < 6; nt++) {
    const int o = cbase + nt * 16 + lrow;
    const float bs = bias[o];
    if (o < 64) {
      float s = 0.f;
      #pragma unroll
      for (int mt = 0; mt < 4; mt++) {
        const int tr = t0 + rbase + mt * 16 + lq * 4;
        #pragma unroll
        for (int r = 0; r < 4; r++) {
          const float v = acc[mt][nt][r] + bs;
          q[w * 65536 + (tr + r) * 64 + o] = (half_t)v;
          s += v;
        }
      }
      atomicAdd(&qs_l[o], s);
    } else if (o < 128) {
      const int oc = o - 64;
      float s = 0.f;
      #pragma unroll
      for (int mt = 0; mt < 4; mt++) {
        const int tr = t0 + rbase + mt * 16 + lq * 4;
        #pragma unroll
        for (int r = 0; r < 4; r++) {
          const float v = acc[mt][nt][r] + bs;
          k[w * 65536 + (tr + r) * 64 + oc] = (half_t)v;
          s += v;
        }
      }
      atomicAdd(&ks_l[oc], s);
    } else {
      const int oc = o - 128;
      #pragma unroll
      for (int mt = 0; mt < 4; mt++) {
        const int tr = t0 + rbase + mt * 16 + lq * 4;
        half4 pk;
        #pragma unroll
        for (int r = 0; r < 4; r++) pk[r] = (half_t)(acc[mt][nt][r] + bs);
        *(half4*)&vT[w * 65536 + oc * 1024 + tr] = pk;
      }
    }
  }
  __syncthreads();
  if (tid < 64) {
    qp[(w * 8 + tx) * 64 + tid] = qs_l[tid];
    kp[(w * 8 + tx) * 64 + tid] = ks_l[tid];
  }
}

// ------------------------------------------------------------------ k_ar ----
// Reduce per-tile partials; arH[i][j] = (half)relu(qsum_i . ksum_j)/1024^2
__global__ __launch_bounds__(256) void k_ar(const float* __restrict__ qp,
                                            const float* __restrict__ kp,
                                            half_t* __restrict__ arH) {
  __shared__ float qs[64][65];
  __shared__ float ks[64][65];
  const int tid = threadIdx.x;
  for (int e = tid; e < 4096; e += 256) {
    const int i = e >> 6, c = e & 63;
    float sq = 0.f, sk = 0.f;
    #pragma unroll
    for (int t = 0; t < 8; t++) {
      sq += qp[i * 512 + t * 64 + c];
      sk += kp[i * 512 + t * 64 + c];
    }
    qs[i][c] = sq;
    ks[i][c] = sk;
  }
  __syncthreads();
  const float scale = 1.f / (1024.f * 1024.f);
  const int e = blockIdx.x * 256 + tid;  // grid 16 -> 4096 outputs
  const int i = e >> 6, j = e & 63;
  float s = 0.f;
  #pragma unroll
  for (int c = 0; c < 64; c++) s += qs[i][c] * ks[j][c];
  s *= scale;
  arH[e] = (half_t)(s > 0.f ? s : 0.f);
}

// ----------------------------------------------------------------- k_mix ----
// MFMA GEMM: D[i][pos] = sum_j arH[i][j] * src[j][pos].  M=64(i), K=64(j),
// N=65536(pos). A-frags = arH rows (b128, L1-hot). B-frags assembled from
// coalesced scalar u16 global loads (lane n=pos). C stored as coalesced u16.
// No LDS, no barriers. grid (256, 2): wave handles 2 pos-tiles of 32.
__global__ __launch_bounds__(256) void k_mix(const half_t* __restrict__ q,
                                             const half_t* __restrict__ k,
                                             const half_t* __restrict__ arH,
                                             half_t* __restrict__ qm,
                                             half_t* __restrict__ km) {
  const half_t* __restrict__ src = blockIdx.y ? k : q;
  half_t* __restrict__ dst = blockIdx.y ? km : qm;
  const int tid = threadIdx.x;
  const int wave = tid >> 6, lane = tid & 63;
  const int ln31 = lane & 31;
  const int hk8 = (lane >> 5) * 8;

  // A-frags: A[m=i][k=j], i = mt*32 + ln31, j = kk*16 + hk8 + jj
  half8 aA[2][4];
  #pragma unroll
  for (int mt = 0; mt < 2; mt++)
    #pragma unroll
    for (int kk = 0; kk < 4; kk++)
      aA[mt][kk] = *(const half8*)&arH[(mt * 32 + ln31) * 64 + kk * 16 + hk8];

  #pragma unroll
  for (int t32 = 0; t32 < 2; t32++) {
    const int pos = blockIdx.x * 256 + wave * 64 + t32 * 32 + ln31;
    // B-frags: B[k=j][n=pos]
    half8 bB[4];
    #pragma unroll
    for (int kk = 0; kk < 4; kk++)
      #pragma unroll
      for (int jj = 0; jj < 8; jj++)
        bB[kk][jj] = src[(kk * 16 + hk8 + jj) * 65536 + pos];

    floatx16 c0, c1;
    #pragma unroll
    for (int r = 0; r < 16; r++) { c0[r] = 0.f; c1[r] = 0.f; }
    #pragma unroll
    for (int kk = 0; kk < 4; kk++) {
      c0 = MFMA32(aA[0][kk], bB[kk], c0);
      c1 = MFMA32(aA[1][kk], bB[kk], c1);
    }
    // store: i = mt*32 + (r&3) + 4*(lane>>5) + 8*(r>>2), coalesced u16
    const int h4 = (lane >> 5) * 4;
    #pragma unroll
    for (int r = 0; r < 16; r++) {
      const int row = (r & 3) + h4 + 8 * (r >> 2);
      dst[row * 65536 + pos] = (half_t)c0[r];
      dst[(32 + row) * 65536 + pos] = (half_t)c1[r];
    }
  }
}

// ---------------------------------------------------------------- k_attn ----
// Per (t-tile of 128, window): O = relu(Qm Km^T) V over 8 s-chunks of 128.
// v3: O^T formulation. S^T = K.Q^T (A=K direct-from-global, B=Q resident);
// St[t][s] pad 138 (odd word stride -> conflict-free half4 writes);
// O^T = V^T.S (A=Vs[c][s], B=St[t][s]) -> C-layout rows=c, cols=t matches
// the out[c][h][w] store directly: no Of LDS round-trip, 128B fp32 stores.
__global__ __launch_bounds__(256, 2) void k_attn(const half_t* __restrict__ qm,
                                                 const half_t* __restrict__ km,
                                                 const half_t* __restrict__ vT,
                                                 float* __restrict__ out) {
  __shared__ __align__(16) half_t Vs[64][136];   // [c][s-chunk]
  __shared__ __align__(16) half_t St[128][138];  // [t][s], pad 138
  const int w = blockIdx.y;
  const int t0 = blockIdx.x * 128;
  const int tid = threadIdx.x;
  const int wave = tid >> 6, lane = tid & 63;
  const int ln31 = lane & 31;
  const int hk8 = (lane >> 5) * 8, hk4 = (lane >> 5) * 4;
  const int w32 = wave * 32;
  const int wbase = w * 65536;

  // Q as B-fragments direct from global: B[n=t][k=c]
  half8 bQ[4][4];
  #pragma unroll
  for (int tt = 0; tt < 4; tt++)
    #pragma unroll
    for (int kk = 0; kk < 4; kk++)
      bQ[tt][kk] = *(const half8*)&qm[wbase + (t0 + tt * 32 + ln31) * 64 + kk * 16 + hk8];

  floatx16 oacc[2];
  #pragma unroll
  for (int ct = 0; ct < 2; ct++)
    #pragma unroll
    for (int r = 0; r < 16; r++) oacc[ct][r] = 0.f;

  for (int sc = 0; sc < 8; sc++) {
    const int s0 = sc * 128;
    __syncthreads();  // previous chunk's Vs/St reads done
    for (int idx = tid; idx < 1024; idx += 256) {
      const int c = idx >> 4, so = (idx & 15) * 8;
      *(half8*)&Vs[c][so] = *(const half8*)&vT[wbase + c * 1024 + s0 + so];
    }
    // K A-frags direct from global (each s-row consumed by exactly one wave)
    half8 aK[4];
    #pragma unroll
    for (int kk = 0; kk < 4; kk++)
      aK[kk] = *(const half8*)&km[wbase + (s0 + w32 + ln31) * 64 + kk * 16 + hk8];
    __syncthreads();  // Vs ready

    // S^T[s][t] = sum_c K[s][c] Q[t][c]; wave owns s-rows [w32, w32+32)
    floatx16 sacc[4];
    #pragma unroll
    for (int tt = 0; tt < 4; tt++)
      #pragma unroll
      for (int r = 0; r < 16; r++) sacc[tt][r] = 0.f;
    #pragma unroll
    for (int kk = 0; kk < 4; kk++)
      #pragma unroll
      for (int tt = 0; tt < 4; tt++)
        sacc[tt] = MFMA32(aK[kk], bQ[tt][kk], sacc[tt]);

    // relu -> packed half4 -> St[t][s] (stride 138 halves = 69 words, odd)
    #pragma unroll
    for (int tt = 0; tt < 4; tt++) {
      const int t = tt * 32 + ln31;
      #pragma unroll
      for (int g = 0; g < 4; g++) {
        const int s = w32 + g * 8 + hk4;
        half4 pk;
        #pragma unroll
        for (int p = 0; p < 4; p++) {
          const float v = sacc[tt][g * 4 + p];
          pk[p] = (half_t)(v > 0.f ? v : 0.f);
        }
        *(half4*)&St[t][s] = pk;
      }
    }
    __syncthreads();  // St ready

    // O^T[c][t] += sum_s V^T[c][s] S[s][t]: A=Vs rows (m=c), B=St rows (n=t)
    #pragma unroll
    for (int kk = 0; kk < 8; kk++) {
      const half8 bS = *(const half8*)&St[w32 + ln31][kk * 16 + hk8];
      #pragma unroll
      for (int ct = 0; ct < 2; ct++) {
        const half8 aV = *(const half8*)&Vs[ct * 32 + ln31][kk * 16 + hk8];
        oacc[ct] = MFMA32(aV, bS, oacc[ct]);
      }
    }
  }

  // Direct store: lane's col t = t0+w32+ln31 (fixed), rows c vary with reg.
  const int ih = w >> 3, iw = w & 7;
  const int obase = ih * 8192 + iw * 32;
  const int tb = ((t0 + w32) >> 5) * 256 + ln31;  // t0+w32 multiple of 32
  const int h4 = (lane >> 5) * 4;
  #pragma unroll
  for (int ct = 0; ct < 2; ct++) {
    #pragma unroll
    for (int r = 0; r < 16; r++) {
      const int c = ct * 32 + (r & 3) + h4 + 8 * (r >> 2);
      out[c * 65536 + obase + tb] = oacc[ct][r];
    }
  }
}

// ---------------------------------------------------------------- launch ----
extern "C" void kernel_launch(void* const* d_in, const int* in_sizes, int n_in,
                              void* d_out, int out_size, void* d_ws, size_t ws_size,
                              hipStream_t stream) {
  const float* x = (const float*)d_in[0];
  const float* W = (const float*)d_in[1];
  const float* bias = (const float*)d_in[2];
  float* out = (float*)d_out;

  half_t* q = (half_t*)d_ws;
  half_t* k = q + 4194304;
  half_t* vT = k + 4194304;
  half_t* qm = vT + 4194304;
  half_t* km = qm + 4194304;
  float* qp = (float*)(km + 4194304);  // 512*64
  float* kp = qp + 32768;
  half_t* arH = (half_t*)(kp + 32768); // 4096, 16B-aligned

  k_qkv<<<dim3(8, 64), 256, 0, stream>>>(x, W, bias, q, k, vT, qp, kp);
  k_ar<<<16, 256, 0, stream>>>(qp, kp, arH);
  k_mix<<<dim3(256, 2), 256, 0, stream>>>(q, k, arH, qm, km);
  k_attn<<<dim3(8, 64), 256, 0, stream>>>(qm, km, vT, out);
}